// Round 5
// baseline (324.668 us; speedup 1.0000x reference)
//
#include <hip/hip_runtime.h>
#include <math.h>

#define ACC_BITS 23

// Params computed once on-device (scalar inputs live in device memory).
struct QParams {
    float scale;
    int   fast;                       // 1 => 24-bit fast path valid
    int   nmx_hi, nmx_lo, Kx, srx12;  // x:  nm split 12/12, K=2^(sr-1), sr-12
    int   nmi_hi, nmi_lo, Ki, sri12;  // id: same
    long long nm_x64, nm_i64;         // generic fallback
    int   e_x, e_i;
};

__global__ void qparams_kernel(const float* __restrict__ pre_sf,
                               const float* __restrict__ id_sf,
                               const float* __restrict__ xminp,
                               const float* __restrict__ xmaxp,
                               QParams* __restrict__ p,
                               float* __restrict__ out_scale)
{
    float s = fmaxf(fmaxf(fabsf(xminp[0]), fabsf(xmaxp[0])), 1e-8f);
    float scale = s / 127.0f;                 // fp32 divide, bit-exact vs reference

    double s64  = (double)scale;
    double ns_x = (double)pre_sf[0] / s64;
    double ns_i = (double)id_sf[0] / s64;

    int e_x, e_i;
    double m_x = frexp(ns_x, &e_x);           // m in [0.5,1)
    double m_i = frexp(ns_i, &e_i);
    long long nm_x = (long long)rint(m_x * 8388608.0);   // round-half-even == jnp.round
    long long nm_i = (long long)rint(m_i * 8388608.0);

    p->scale  = scale;
    p->nm_x64 = nm_x;  p->e_x = e_x;
    p->nm_i64 = nm_i;  p->e_i = e_i;

    // Normalize nm == 2^23 -> (2^22, e+1): result-identical (rounded numerator
    // is even, so the -bit nudge can't cross a floor boundary differently).
    long long ax = nm_x, ai = nm_i;
    int ex = e_x, ei = e_i;
    if (ax == (1LL << 23)) { ax >>= 1; ex += 1; }
    if (ai == (1LL << 23)) { ai >>= 1; ei += 1; }
    int sr_x = ACC_BITS - ex, sr_i = ACC_BITS - ei;

    int fast = (ax > 0) && (ax < (1LL << 23)) &&
               (ai > 0) && (ai < (1LL << 23)) &&
               (sr_x >= 12) && (sr_x <= 30) && (sr_i >= 12) && (sr_i <= 30);
    p->fast = fast;
    p->nmx_hi = (int)(ax >> 12); p->nmx_lo = (int)(ax & 0xFFF);
    p->nmi_hi = (int)(ai >> 12); p->nmi_lo = (int)(ai & 0xFFF);
    p->Kx = fast ? (1 << (sr_x - 1)) : 0;
    p->Ki = fast ? (1 << (sr_i - 1)) : 0;
    p->srx12 = sr_x - 12;
    p->sri12 = sr_i - 12;

    *out_scale = scale;                       // tuple output 1
}

// Generic bit-exact replica (fallback + tails).
__device__ __forceinline__ long long fixed_point_mul64(long long xi, long long nm, int e) {
    long long tmp = xi * nm;
    if (e - ACC_BITS >= 0) {
        return tmp << (e - ACC_BITS);
    } else {
        int sr = ACC_BITS - e;
        long long nudge = (1LL << (sr - 1)) - (long long)(tmp < 0);
        return (tmp + nudge) >> sr;
    }
}

// Full-rate 24-bit-multiply fixed-point mul (bit-exact for |xi|<2^19,
// 0<nm<2^23, 12<=sr<=30; verified absmax=0 in R3/R4).
__device__ __forceinline__ int fpm24(int xi, int nm_hi, int nm_lo, int K, int sr12) {
    int bit = (int)((unsigned)xi >> 31);
    int B = (__mul24(xi, nm_lo) + K - bit) >> 12;
    int A = __mul24(xi, nm_hi);
    return (A + B) >> sr12;
}

typedef float f32x4 __attribute__((ext_vector_type(4)));

#define TPB   256
#define VPT   2                       // f32x4 per thread per tile
#define TILEV (TPB * VPT)             // 512 f32x4 per tile

// Persistent software-pipelined kernel: depth-2 ping-pong register pipeline.
// Loads for tile j+G are issued BEFORE computing/storing tile j, so each wave
// keeps 4 loads (4 KiB) outstanding continuously across its whole lifetime
// (R4's one-shot form drained to zero at every block boundary -> 110us).
__global__ void __launch_bounds__(TPB)
quantact_main(const f32x4* __restrict__ x,
              const f32x4* __restrict__ idn,
              f32x4* __restrict__ out,
              const QParams* __restrict__ p,
              int n4, int n, int tiles)
{
    const float scale = p->scale;
    const int tid = threadIdx.x;
    const int G = gridDim.x;

    if (p->fast) {
        const int nmx_hi = p->nmx_hi, nmx_lo = p->nmx_lo, Kx = p->Kx, srx = p->srx12;
        const int nmi_hi = p->nmi_hi, nmi_lo = p->nmi_lo, Ki = p->Ki, sri = p->sri12;

        f32x4 xa0, xa1, ia0, ia1;     // stage A
        f32x4 xb0, xb1, ib0, ib1;     // stage B

        auto LOADA = [&](int j) {
            int b = j * TILEV + tid;
            xa0 = x[b]; xa1 = x[b + TPB]; ia0 = idn[b]; ia1 = idn[b + TPB];
        };
        auto LOADB = [&](int j) {
            int b = j * TILEV + tid;
            xb0 = x[b]; xb1 = x[b + TPB]; ib0 = idn[b]; ib1 = idn[b + TPB];
        };
        auto CS = [&](int j, f32x4& xv0, f32x4& iv0, f32x4& xv1, f32x4& iv1) {
            int b = j * TILEV + tid;
            f32x4 o0, o1;
            #pragma unroll
            for (int c = 0; c < 4; ++c) {
                int q0 = fpm24((int)xv0[c], nmx_hi, nmx_lo, Kx, srx)
                       + fpm24((int)iv0[c], nmi_hi, nmi_lo, Ki, sri);
                q0 = q0 < -128 ? -128 : (q0 > 127 ? 127 : q0);   // v_med3_i32
                o0[c] = (float)q0 * scale;
                int q1 = fpm24((int)xv1[c], nmx_hi, nmx_lo, Kx, srx)
                       + fpm24((int)iv1[c], nmi_hi, nmi_lo, Ki, sri);
                q1 = q1 < -128 ? -128 : (q1 > 127 ? 127 : q1);
                o1[c] = (float)q1 * scale;
            }
            out[b] = o0;
            out[b + TPB] = o1;
        };

        int j = blockIdx.x;
        if (j < tiles) {
            LOADA(j);
            for (;;) {
                int j2 = j + G;
                if (j2 >= tiles) { CS(j, xa0, ia0, xa1, ia1); break; }
                LOADB(j2);                       // B in flight across A's compute+store
                CS(j, xa0, ia0, xa1, ia1);
                int j3 = j2 + G;
                if (j3 >= tiles) { CS(j2, xb0, ib0, xb1, ib1); break; }
                LOADA(j3);                       // A in flight across B's compute+store
                CS(j2, xb0, ib0, xb1, ib1);
                j = j3;
            }
        }

        // vector remainder [tiles*TILEV, n4) — block 0, generic exact path
        if (blockIdx.x == 0) {
            const long long nm64_x = p->nm_x64, nm64_i = p->nm_i64;
            const int e_x = p->e_x, e_i = p->e_i;
            for (int i = tiles * TILEV + tid; i < n4; i += TPB) {
                f32x4 xv = x[i], iv = idn[i], ov;
                #pragma unroll
                for (int c = 0; c < 4; ++c) {
                    long long o = fixed_point_mul64((long long)xv[c], nm64_x, e_x)
                                + fixed_point_mul64((long long)iv[c], nm64_i, e_i);
                    o = o < -128 ? -128 : (o > 127 ? 127 : o);
                    ov[c] = (float)(int)o * scale;
                }
                out[i] = ov;
            }
        }
    } else {
        // Generic path: exact 64-bit replica, covers all of [0, n4).
        const long long nm64_x = p->nm_x64, nm64_i = p->nm_i64;
        const int e_x = p->e_x, e_i = p->e_i;
        for (int i = blockIdx.x * TPB + tid; i < n4; i += G * TPB) {
            f32x4 xv = x[i], iv = idn[i], ov;
            #pragma unroll
            for (int c = 0; c < 4; ++c) {
                long long o = fixed_point_mul64((long long)xv[c], nm64_x, e_x)
                            + fixed_point_mul64((long long)iv[c], nm64_i, e_i);
                o = o < -128 ? -128 : (o > 127 ? 127 : o);
                ov[c] = (float)(int)o * scale;
            }
            out[i] = ov;
        }
    }

    // scalar tail for n % 4 != 0 (not hit at this shape)
    if (blockIdx.x == 0) {
        const float* xs  = (const float*)x;
        const float* is_ = (const float*)idn;
        float* os = (float*)out;
        const long long nm64_x = p->nm_x64, nm64_i = p->nm_i64;
        const int e_x = p->e_x, e_i = p->e_i;
        for (int j2 = n4 * 4 + tid; j2 < n; j2 += TPB) {
            long long o = fixed_point_mul64((long long)xs[j2], nm64_x, e_x)
                        + fixed_point_mul64((long long)is_[j2], nm64_i, e_i);
            o = o < -128 ? -128 : (o > 127 ? 127 : o);
            os[j2] = (float)(int)o * scale;
        }
    }
}

extern "C" void kernel_launch(void* const* d_in, const int* in_sizes, int n_in,
                              void* d_out, int out_size, void* d_ws, size_t ws_size,
                              hipStream_t stream) {
    const f32x4* x      = (const f32x4*)d_in[0];
    const f32x4* idn    = (const f32x4*)d_in[1];
    const float* pre_sf = (const float*)d_in[2];
    const float* id_sf  = (const float*)d_in[3];
    const float* xmin   = (const float*)d_in[4];
    const float* xmax   = (const float*)d_in[5];

    int n  = in_sizes[0];          // 33,554,432
    int n4 = n / 4;                // 8,388,608 f32x4
    int tiles = n4 / TILEV;        // 16384 full tiles

    float* out       = (float*)d_out;
    float* out_scale = out + n;    // tuple output 1 (flat-concatenated)
    QParams* p       = (QParams*)d_ws;

    qparams_kernel<<<1, 1, 0, stream>>>(pre_sf, id_sf, xmin, xmax, p, out_scale);

    // 2048 blocks = 8 blocks/CU, all co-resident at <=64 VGPR (8 waves/SIMD);
    // each block runs 8 pipelined tile iterations -> no relaunch drain.
    int grid = 2048;
    if (tiles > 0 && tiles < grid) grid = tiles;
    if (grid < 1) grid = 1;
    quantact_main<<<grid, TPB, 0, stream>>>(x, idn, (f32x4*)out, p, n4, n, tiles);
}